// Round 15
// baseline (185.590 us; speedup 1.0000x reference)
//
#include <hip/hip_runtime.h>

// ---------------- problem constants ----------------
#define DIMC 1024
#define NH   16
#define HD   64
#define BSZ  2
#define TSZ  2048
#define MROWS (BSZ*TSZ)   // 4096

typedef __attribute__((ext_vector_type(8))) short s16x8;   // 8 bf16 (4 VGPRs)
typedef __attribute__((ext_vector_type(4))) float f32x4;   // 4 fp32

__device__ __forceinline__ float b2f(unsigned short u) {
  return __uint_as_float(((unsigned)u) << 16);
}
__device__ __forceinline__ unsigned short f2b(float f) {
  unsigned x = __float_as_uint(f);
  unsigned r = x + 0x7fffu + ((x >> 16) & 1u);   // RTNE
  return (unsigned short)(r >> 16);
}
// single-instruction packed f32->bf16 (RTNE), lo = a, hi = b  [T12 recipe]
__device__ __forceinline__ unsigned pk2(float a, float b) {
  unsigned r;
  asm("v_cvt_pk_bf16_f32 %0, %1, %2" : "=v"(r) : "v"(a), "v"(b));
  return r;
}
// 2^x in one v_exp_f32 (softmax runs in log2 domain)
__device__ __forceinline__ float ex2(float x) {
#if __has_builtin(__builtin_amdgcn_exp2f)
  return __builtin_amdgcn_exp2f(x);
#else
  float r; asm("v_exp_f32 %0, %1" : "=v"(r) : "v"(x)); return r;
#endif
}
__device__ __forceinline__ float ldsc(const void* __restrict__ p, int idx, int isf32) {
  return isf32 ? ((const float*)p)[idx] : b2f(((const unsigned short*)p)[idx]);
}

// 16-byte global -> LDS DMA. lds base wave-uniform; HW writes lane i at base+16i.
__device__ __forceinline__ void async_cp16(const unsigned short* g, unsigned short* l) {
  __builtin_amdgcn_global_load_lds(
      (const __attribute__((address_space(1))) unsigned int*)g,
      (__attribute__((address_space(3))) unsigned int*)l, 16, 0, 0);
}

// ---------------------------------------------------------------------------
// fp32 -> bf16 conversion of x, w_qkv, w_out with INLINE dtype detection
// (folds the old detect_dtype kernel: each wave ballots over cosp[0..63];
// fp32 inputs have interleaved mantissa halves >= 0x4000, bf16 cos values
// in [0,1) never do). Block 0 publishes dflag for the downstream GEMMs
// (kernel-boundary coherence). One fewer launch in the graph.
// ---------------------------------------------------------------------------
__global__ __launch_bounds__(256)
void cvt_all(const float* __restrict__ x, const float* __restrict__ wq,
             const float* __restrict__ wo, const unsigned short* __restrict__ cosp16,
             unsigned short* __restrict__ xb, unsigned short* __restrict__ wqb,
             unsigned short* __restrict__ wob, int* __restrict__ dflag) {
  const int tid = threadIdx.x;
  const unsigned long long m = __ballot(cosp16[tid & 63] >= 0x4000u);
  const int flag = (m != 0ull) ? 1 : 0;
  if (blockIdx.x == 0 && tid == 0) *dflag = flag;
  if (!flag) return;                                   // inputs already bf16
  const unsigned id = blockIdx.x * 256 + tid;          // 0..1048575
  const float* src; unsigned short* dst; unsigned off;
  if (id < 524288u) { src = x; dst = xb; off = id; }
  else if (id < 917504u) { src = wq; dst = wqb; off = id - 524288u; }
  else { src = wo; dst = wob; off = id - 917504u; }
  const float4 a = ((const float4*)src)[off * 2];
  const float4 b = ((const float4*)src)[off * 2 + 1];
  uint4 u;
  u.x = pk2(a.x, a.y); u.y = pk2(a.z, a.w);
  u.z = pk2(b.x, b.y); u.w = pk2(b.z, b.w);
  ((uint4*)dst)[off] = u;
}

// ---------------------------------------------------------------------------
// QKV projection GEMM, 128x128 tile, 512 threads / 8 waves, BK=64, K=1024.
// 2-phase pipeline (issue-early / wait-late). Epilogue: RoPE (q pre-scaled
// by 0.125*log2e), per-wave 32x64 LDS transpose tile, coalesced uint4
// scatter into q/k/v [B,H,T,64] bf16.
// ---------------------------------------------------------------------------
__global__ __launch_bounds__(512, 4)
void gemm_qkv128(const void* __restrict__ Aorig, const unsigned short* __restrict__ Aconv,
                 const void* __restrict__ Worig, const unsigned short* __restrict__ Wconv,
                 const void* __restrict__ cosp, const void* __restrict__ sinp,
                 unsigned short* __restrict__ qout,
                 unsigned short* __restrict__ kout,
                 unsigned short* __restrict__ vout,
                 const int* __restrict__ dflag) {
  const int f32flag = *dflag;
  const unsigned short* A = f32flag ? Aconv : (const unsigned short*)Aorig;
  const unsigned short* W = f32flag ? Wconv : (const unsigned short*)Worig;

  const int tid = threadIdx.x;
  const int m0 = blockIdx.y * 128;
  const int n0 = blockIdx.x * 128;

  __shared__ __align__(16) unsigned short s_ab[2 * 16384];

  const int lane = tid & 63;
  const int wave = tid >> 6;               // 0..7
  const int wm = (wave & 3) * 32;
  const int wn = (wave >> 2) * 64;
  const int m16 = lane & 15;
  const int quad = lane >> 4;

  const int srow = lane >> 3;
  const int schunk = (lane & 7) ^ srow;

  const unsigned short* ga = A + (size_t)(m0 + wave * 8 + srow) * DIMC + schunk * 8;
  const unsigned short* gb = W + (size_t)(n0 + wave * 8 + srow) * DIMC + schunk * 8;

  f32x4 acc[2][4];
#pragma unroll
  for (int i = 0; i < 2; ++i)
#pragma unroll
    for (int j = 0; j < 4; ++j) acc[i][j] = (f32x4){0.f, 0.f, 0.f, 0.f};

  auto stage = [&](int b, int kt) {
    unsigned short* sa = s_ab + b * 16384;
#pragma unroll
    for (int u = 0; u < 2; ++u) {
      async_cp16(ga + (size_t)(u * 64) * DIMC + kt, &sa[(u * 64 + wave * 8) * 64]);
      async_cp16(gb + (size_t)(u * 64) * DIMC + kt, &sa[8192 + (u * 64 + wave * 8) * 64]);
    }
  };

  stage(0, 0);
  __syncthreads();

  for (int t = 0; t < 16; ++t) {
    const int cur = t & 1;
    if (t < 15) stage(cur ^ 1, (t + 1) * 64);
    const unsigned short* sa = s_ab + cur * 16384;
    const unsigned short* sb = sa + 8192;
    __builtin_amdgcn_s_setprio(1);
#pragma unroll
    for (int kk = 0; kk < 64; kk += 32) {
      const int cx = ((kk >> 3) + quad) ^ (m16 & 7);
      s16x8 af[2], bf[4];
#pragma unroll
      for (int i = 0; i < 2; ++i)
        af[i] = *(const s16x8*)&sa[(wm + i * 16 + m16) * 64 + cx * 8];
#pragma unroll
      for (int j = 0; j < 4; ++j)
        bf[j] = *(const s16x8*)&sb[(wn + j * 16 + m16) * 64 + cx * 8];
#pragma unroll
      for (int i = 0; i < 2; ++i)
#pragma unroll
        for (int j = 0; j < 4; ++j)
          acc[i][j] = __builtin_amdgcn_mfma_f32_16x16x32_bf16(af[i], bf[j], acc[i][j], 0, 0, 0);
    }
    __builtin_amdgcn_s_setprio(0);
    __syncthreads();
  }

  const int sel = n0 >> 10;
  const int h = ((n0 & 1023) >> 6) + (wave >> 2);
  unsigned short* dst = (sel == 0) ? qout : ((sel == 1) ? kout : vout);
  const float qsc = (sel == 0) ? 0.18033688f : 1.0f;
  unsigned short* tile = s_ab + wave * 2048;
  if (sel < 2) {
#pragma unroll
    for (int i = 0; i < 2; ++i)
#pragma unroll
      for (int r = 0; r < 4; ++r) {
        const int row_l = i * 16 + quad * 4 + r;
        const int t = (m0 + wm + row_l) & 2047;
#pragma unroll
        for (int jg = 0; jg < 2; ++jg) {
          const int d = jg * 16 + m16;
          const float c = ldsc(cosp, t * 32 + d, f32flag);
          const float sn = ldsc(sinp, t * 32 + d, f32flag);
          const float v1 = acc[i][jg][r];
          const float v2 = acc[i][jg + 2][r];
          tile[row_l * 64 + d]      = f2b((v1 * c - v2 * sn) * qsc);
          tile[row_l * 64 + d + 32] = f2b((v1 * sn + v2 * c) * qsc);
        }
      }
  } else {
#pragma unroll
    for (int i = 0; i < 2; ++i)
#pragma unroll
      for (int r = 0; r < 4; ++r) {
        const int row_l = i * 16 + quad * 4 + r;
#pragma unroll
        for (int j = 0; j < 4; ++j)
          tile[row_l * 64 + j * 16 + m16] = f2b(acc[i][j][r]);
      }
  }
#pragma unroll
  for (int s = 0; s < 4; ++s) {
    const int row_l = s * 8 + (lane >> 3);
    const int seg = lane & 7;
    const int mrow_ = m0 + wm + row_l;
    const int bb = mrow_ >> 11;
    const int t = mrow_ & 2047;
    unsigned short* drow = dst + (((size_t)(bb * NH + h)) * TSZ + t) * HD;
    *(uint4*)(drow + seg * 8) = *(const uint4*)&tile[row_l * 64 + seg * 8];
  }
}

// ---------------------------------------------------------------------------
// Out-projection GEMM: 128x64 tile, 256 threads / 4 waves, 2-phase
// issue-early/wait-late pipeline (LDS 2 x 24 KB). fp32 epilogue: per-wave
// 32x68-stride LDS transpose then coalesced float4 stores.
// ---------------------------------------------------------------------------
__global__ __launch_bounds__(256)
void gemm_out(const void* __restrict__ Aorig, const unsigned short* __restrict__ Aconv,
              const void* __restrict__ Worig, const unsigned short* __restrict__ Wconv,
              void* __restrict__ C, const int* __restrict__ dflag, int Nsz) {
  const int f32flag = *dflag;
  const unsigned short* A = f32flag ? Aconv : (const unsigned short*)Aorig;
  const unsigned short* W = f32flag ? Wconv : (const unsigned short*)Worig;

  const int tid = threadIdx.x;
  const int m0 = blockIdx.y * 128;
  const int n0 = blockIdx.x * 64;

  __shared__ __align__(16) unsigned short s_ab[2 * 12288];

  const int lane = tid & 63;
  const int wave = tid >> 6;               // 0..3
  const int wm = wave * 32;
  const int m16 = lane & 15;
  const int quad = lane >> 4;

  const int srow = lane >> 3;
  const int schunk = (lane & 7) ^ srow;

  const unsigned short* ga = A + (size_t)(m0 + wave * 8 + srow) * DIMC + schunk * 8;
  const unsigned short* gb = W + (size_t)(n0 + wave * 8 + srow) * DIMC + schunk * 8;

  f32x4 acc[2][4];
#pragma unroll
  for (int i = 0; i < 2; ++i)
#pragma unroll
    for (int j = 0; j < 4; ++j) acc[i][j] = (f32x4){0.f, 0.f, 0.f, 0.f};

  auto stage = [&](int b, int kt) {
    unsigned short* sa = s_ab + b * 12288;
#pragma unroll
    for (int u = 0; u < 4; ++u)
      async_cp16(ga + (size_t)(u * 32) * DIMC + kt, &sa[(u * 32 + wave * 8) * 64]);
#pragma unroll
    for (int u = 0; u < 2; ++u)
      async_cp16(gb + (size_t)(u * 32) * DIMC + kt, &sa[8192 + (u * 32 + wave * 8) * 64]);
  };

  stage(0, 0);
  __syncthreads();

  for (int t = 0; t < 16; ++t) {
    const int cur = t & 1;
    if (t < 15) stage(cur ^ 1, (t + 1) * 64);
    const unsigned short* sa = s_ab + cur * 12288;
    const unsigned short* sb = sa + 8192;
    __builtin_amdgcn_s_setprio(1);
#pragma unroll
    for (int kk = 0; kk < 64; kk += 32) {
      const int cx = ((kk >> 3) + quad) ^ (m16 & 7);
      s16x8 af[2], bf[4];
#pragma unroll
      for (int i = 0; i < 2; ++i)
        af[i] = *(const s16x8*)&sa[(wm + i * 16 + m16) * 64 + cx * 8];
#pragma unroll
      for (int j = 0; j < 4; ++j)
        bf[j] = *(const s16x8*)&sb[(j * 16 + m16) * 64 + cx * 8];
#pragma unroll
      for (int i = 0; i < 2; ++i)
#pragma unroll
        for (int j = 0; j < 4; ++j)
          acc[i][j] = __builtin_amdgcn_mfma_f32_16x16x32_bf16(af[i], bf[j], acc[i][j], 0, 0, 0);
    }
    __builtin_amdgcn_s_setprio(0);
    __syncthreads();
  }

  if (f32flag) {
    float* ftile = (float*)s_ab + wave * (32 * 68);
#pragma unroll
    for (int i = 0; i < 2; ++i)
#pragma unroll
      for (int j = 0; j < 4; ++j)
#pragma unroll
        for (int r = 0; r < 4; ++r)
          ftile[(i * 16 + quad * 4 + r) * 68 + j * 16 + m16] = acc[i][j][r];
    float* Cf = (float*)C;
#pragma unroll
    for (int i = 0; i < 2; ++i)
#pragma unroll
      for (int s = 0; s < 4; ++s) {
        const int row_l = i * 16 + s * 4 + (lane >> 4);
        const float4 vv = *(const float4*)&ftile[row_l * 68 + (lane & 15) * 4];
        *(float4*)&Cf[(size_t)(m0 + wm + row_l) * Nsz + n0 + (lane & 15) * 4] = vv;
      }
  } else {
    unsigned short* Ch = (unsigned short*)C;
#pragma unroll
    for (int i = 0; i < 2; ++i)
#pragma unroll
      for (int j = 0; j < 4; ++j)
#pragma unroll
        for (int r = 0; r < 4; ++r) {
          const int mrow_ = m0 + wm + i * 16 + quad * 4 + r;
          const int col = n0 + j * 16 + m16;
          Ch[(size_t)mrow_ * Nsz + col] = f2b(acc[i][j][r]);
        }
  }
}

// ---------------------------------------------------------------------------
// MFMA flash attention — round-8 structure (best measured: 44.2-44.6 us,
// three consistent runs). S^T form, 512 threads (8 waves), KVBLK=128,
// XOR-swizzled K/V^T/P LDS (64 KB, 2 blocks/CU = 16 waves/CU, grid-capped).
// Post-r14 ledger: wave-widening (r9), K-from-global (r12), tree-reduce
// (r13), speculative defer-max (r14) all regressed or neutral — the kernel
// is latency-bound on a chain that resists source-level attack; this is
// the best-known configuration. Front/back mirror subtile fusion,
// log2-domain softmax, defer-max THR=8, cvt_pk packing, setprio.
// ---------------------------------------------------------------------------
__global__ __launch_bounds__(512, 4)
void attn_fwd_mfma(const unsigned short* __restrict__ qg,
                   const unsigned short* __restrict__ kg,
                   const unsigned short* __restrict__ vg,
                   unsigned short* __restrict__ outg) {
  const int tid = threadIdx.x;
  const int lane = tid & 63;
  const int w = tid >> 6;                // wave 0..7
  const int m16 = lane & 15;
  const int quad = lane >> 4;
  const int sw = m16 & 7;                // row-XOR swizzle key for this lane
  const int l = (int)blockIdx.x;         // 0..511
  const int g = (l & 255) >> 5;          // 0..7
  const int p = (l < 256) ? g : (15 - g);
  const int nc = (33 - p) >> 1;          // 128-key chunks for back subtile 31-p
  const int bh = l & 31;
  const int b = bh >> 4, h = bh & 15;
  const size_t base = (size_t)bh * TSZ * HD;
  const int sub = (w < 4) ? p : (31 - p);
  const int qs = sub * 64 + (w & 3) * 16;   // wave's first query row

  __shared__ __align__(16) unsigned short s_k[128 * 64];   // K rows (16 KB)
  __shared__ __align__(16) unsigned short s_v[64 * 128];   // V^T (16 KB)
  __shared__ __align__(16) unsigned short s_p[128 * 128];  // P + epilogue (32 KB)

  const unsigned short* qgh = qg + base;
  const unsigned short* kgh = kg + base;
  const unsigned short* vgh = vg + base;

  const unsigned short* qrow = qgh + (size_t)(qs + m16) * HD;
  const s16x8 bq0 = *(const s16x8*)(qrow + quad * 8);
  const s16x8 bq1 = *(const s16x8*)(qrow + 32 + quad * 8);

  f32x4 oacc[4];
#pragma unroll
  for (int dt = 0; dt < 4; ++dt) oacc[dt] = (f32x4){0.f, 0.f, 0.f, 0.f};
  float m_ = -1e30f, l_ = 0.f;

  const int krow = tid >> 3, kseg = tid & 7;   // K: 2 rows/thread (r, r+64)
  const int vkey = tid & 63, vseg = tid >> 6;  // V: keys (vkey, vkey+64), 8 d
  const int kcol = (kseg ^ (krow & 7)) * 8;    // swizzled K LDS column
  const int vc0 = vkey >> 3, vo0 = vkey & 7;   // V key chunk / within-chunk

  {  // prologue: chunk 0 into LDS (swizzled)
    const uint4 a0 = *(const uint4*)(kgh + (size_t)krow * HD + kseg * 8);
    const uint4 a1 = *(const uint4*)(kgh + (size_t)(64 + krow) * HD + kseg * 8);
    const uint4 b0 = *(const uint4*)(vgh + (size_t)vkey * HD + vseg * 8);
    const uint4 b1 = *(const uint4*)(vgh + (size_t)(64 + vkey) * HD + vseg * 8);
    *(uint4*)&s_k[krow * 64 + kcol] = a0;
    *(uint4*)&s_k[(64 + krow) * 64 + kcol] = a1;
    const unsigned short* v0 = (const unsigned short*)&b0;
    const unsigned short* v1 = (const unsigned short*)&b1;
#pragma unroll
    for (int jj = 0; jj < 8; ++jj) {
      const int dr = (vseg * 8 + jj) * 128;
      s_v[dr + (vc0 ^ jj) * 8 + vo0] = v0[jj];
      s_v[dr + ((8 + vc0) ^ jj) * 8 + vo0] = v1[jj];
    }
  }

  for (int kc = 0; kc < nc; ++kc) {
    __syncthreads();                     // chunk kc staged & visible
    uint4 a0, a1, b0, b1;
    const int pf = (kc + 1 < nc);
    if (pf) {                            // prefetch next chunk (flies in regs)
      const size_t ko = (size_t)(kc + 1) * 128;
      a0 = *(const uint4*)(kgh + (ko + krow) * HD + kseg * 8);
      a1 = *(const uint4*)(kgh + (ko + 64 + krow) * HD + kseg * 8);
      b0 = *(const uint4*)(vgh + (ko + vkey) * HD + vseg * 8);
      b1 = *(const uint4*)(vgh + (ko + 64 + vkey) * HD + vseg * 8);
    }

    if (kc * 128 <= qs + 15) {           // not fully masked for this wave
      f32x4 sacc[8];
#pragma unroll
      for (int jt = 0; jt < 8; ++jt) sacc[jt] = (f32x4){0.f, 0.f, 0.f, 0.f};
      __builtin_amdgcn_s_setprio(1);
#pragma unroll
      for (int jt = 0; jt < 8; ++jt) {
        const int krb = (jt * 16 + m16) * 64;
        const s16x8 ak0 = *(const s16x8*)&s_k[krb + (quad ^ sw) * 8];
        sacc[jt] = __builtin_amdgcn_mfma_f32_16x16x32_bf16(ak0, bq0, sacc[jt], 0, 0, 0);
        const s16x8 ak1 = *(const s16x8*)&s_k[krb + ((4 + quad) ^ sw) * 8];
        sacc[jt] = __builtin_amdgcn_mfma_f32_16x16x32_bf16(ak1, bq1, sacc[jt], 0, 0, 0);
      }
      __builtin_amdgcn_s_setprio(0);

      if (kc * 128 + 127 > qs) {         // diagonal region: element mask
#pragma unroll
        for (int jt = 0; jt < 8; ++jt)
#pragma unroll
          for (int r = 0; r < 4; ++r)
            if (kc * 128 + jt * 16 + quad * 4 + r > qs + m16) sacc[jt][r] = -1e30f;
      }

      float mx = sacc[0][0];
#pragma unroll
      for (int jt = 0; jt < 8; ++jt)
#pragma unroll
        for (int r = 0; r < 4; ++r) mx = fmaxf(mx, sacc[jt][r]);
      mx = fmaxf(mx, __shfl_xor(mx, 16, 64));
      mx = fmaxf(mx, __shfl_xor(mx, 32, 64));
      if (!__all(mx <= m_ + 8.0f)) {     // defer-max
        const float mn = fmaxf(m_, mx);
        const float alpha = ex2(m_ - mn);
        m_ = mn;
        l_ *= alpha;
#pragma unroll
        for (int dt = 0; dt < 4; ++dt)
#pragma unroll
          for (int r = 0; r < 4; ++r) oacc[dt][r] *= alpha;
      }
      float rs = 0.f;
#pragma unroll
      for (int jt = 0; jt < 8; ++jt)
#pragma unroll
        for (int r = 0; r < 4; ++r) {
          const float pv_ = ex2(sacc[jt][r] - m_);
          sacc[jt][r] = pv_;
          rs += pv_;
        }
      rs += __shfl_xor(rs, 16, 64);
      rs += __shfl_xor(rs, 32, 64);
      l_ += rs;

      const int prb = (w * 16 + m16) * 128;
#pragma unroll
      for (int jt = 0; jt < 8; ++jt) {
        uint2 pw;
        pw.x = pk2(sacc[jt][0], sacc[jt][1]);
        pw.y = pk2(sacc[jt][2], sacc[jt][3]);
        *(uint2*)&s_p[prb + ((jt * 2 + (quad >> 1)) ^ sw) * 8 + (quad & 1) * 4] = pw;
      }

      __builtin_amdgcn_s_setprio(1);
#pragma unroll
      for (int kk = 0; kk < 128; kk += 32) {
        const int cx = (((kk >> 3) + quad) ^ sw) * 8;
        const s16x8 bp = *(const s16x8*)&s_p[prb + cx];
#pragma unroll
        for (int dt = 0; dt < 4; ++dt) {
          const s16x8 av = *(const s16x8*)&s_v[(dt * 16 + m16) * 128 + cx];
          oacc[dt] = __builtin_amdgcn_mfma_f32_16x16x32_bf16(av, bp, oacc[dt], 0, 0, 0);
        }
      }
      __builtin_amdgcn_s_setprio(0);
    }

    __syncthreads();                     // all reads of chunk kc done
    if (pf) {                            // single-buffer write of chunk kc+1
      *(uint4*)&s_k[krow * 64 + kcol] = a0;
      *(uint4*)&s_k[(64 + krow) * 64 + kcol] = a1;
      const unsigned short* v0 = (const unsigned short*)&b0;
      const unsigned short* v1 = (const unsigned short*)&b1;
#pragma unroll
      for (int jj = 0; jj < 8; ++jj) {
        const int dr = (vseg * 8 + jj) * 128;
        s_v[dr + (vc0 ^ jj) * 8 + vo0] = v0[jj];
        s_v[dr + ((8 + vc0) ^ jj) * 8 + vo0] = v1[jj];
      }
    }
  }

  // epilogue: normalize, transpose via wave-private s_p rows, coalesced store
  const float linv = 1.0f / l_;
  {
    const int prb = (w * 16 + m16) * 128;
#pragma unroll
    for (int dt = 0; dt < 4; ++dt) {
      uint2 ow;
      ow.x = pk2(oacc[dt][0] * linv, oacc[dt][1] * linv);
      ow.y = pk2(oacc[dt][2] * linv, oacc[dt][3] * linv);
      *(uint2*)&s_p[prb + ((dt * 2 + (quad >> 1)) ^ sw) * 8 + (quad & 1) * 4] = ow;
    }
  }
  {
    const int qq = lane >> 2, dseg = lane & 3;   // wave-private rows: no barrier
    const int swq = qq & 7;
    const int qrb = (w * 16 + qq) * 128;
    const uint4 o0 = *(const uint4*)&s_p[qrb + ((dseg * 2) ^ swq) * 8];
    const uint4 o1 = *(const uint4*)&s_p[qrb + ((dseg * 2 + 1) ^ swq) * 8];
    unsigned short* orow =
        outg + ((size_t)b * TSZ + qs + qq) * DIMC + h * 64 + dseg * 16;
    *(uint4*)orow = o0;
    *(uint4*)(orow + 8) = o1;
  }
}

// ---------------------------------------------------------------------------
extern "C" void kernel_launch(void* const* d_in, const int* in_sizes, int n_in,
                              void* d_out, int out_size, void* d_ws, size_t ws_size,
                              hipStream_t stream) {
  (void)in_sizes; (void)n_in; (void)out_size; (void)ws_size;
  const void* x    = d_in[0];
  const void* cosp = d_in[1];
  const void* sinp = d_in[2];
  const void* wqkv = d_in[3];
  const void* wout = d_in[4];

  int* dflag = (int*)d_ws;
  const size_t per = (size_t)BSZ * NH * TSZ * HD;       // 4,194,304 elems
  unsigned short* q = (unsigned short*)((char*)d_ws + 256);
  unsigned short* k = q + per;
  unsigned short* v = k + per;
  unsigned short* attnb = v + per;                      // [B,T,DIM] bf16
  unsigned short* xb   = attnb + (size_t)MROWS * DIMC;  // bf16 copies (fp32 case)
  unsigned short* wqb  = xb + (size_t)MROWS * DIMC;
  unsigned short* wob  = wqb + (size_t)3 * DIMC * DIMC;

  // fp32->bf16 conversion with inline dtype detection (writes dflag)
  cvt_all<<<dim3(4096), dim3(256), 0, stream>>>(
      (const float*)x, (const float*)wqkv, (const float*)wout,
      (const unsigned short*)cosp, xb, wqb, wob, dflag);
  // QKV projection: 128x128 tiles, 512 threads, 2-phase pipeline
  gemm_qkv128<<<dim3(3 * DIMC / 128, MROWS / 128), dim3(512), 0, stream>>>(
      x, xb, wqkv, wqb, cosp, sinp, q, k, v, dflag);
  // causal flash attention: round-8 best (512 blocks x 8 waves, KVBLK=128)
  attn_fwd_mfma<<<dim3(512), dim3(512), 0, stream>>>(q, k, v, attnb);
  // out-projection: 128x64 tiles, 256 threads, 2-phase pipeline
  gemm_out<<<dim3(DIMC / 64, MROWS / 128), dim3(256), 0, stream>>>(
      attnb, attnb, wout, wob, d_out, dflag, DIMC);
}

// Round 16
// 173.569 us; speedup vs baseline: 1.0693x; 1.0693x over previous
//
#include <hip/hip_runtime.h>

// ---------------- problem constants ----------------
#define DIMC 1024
#define NH   16
#define HD   64
#define BSZ  2
#define TSZ  2048
#define MROWS (BSZ*TSZ)   // 4096

typedef __attribute__((ext_vector_type(8))) short s16x8;   // 8 bf16 (4 VGPRs)
typedef __attribute__((ext_vector_type(4))) float f32x4;   // 4 fp32

__device__ __forceinline__ float b2f(unsigned short u) {
  return __uint_as_float(((unsigned)u) << 16);
}
__device__ __forceinline__ unsigned short f2b(float f) {
  unsigned x = __float_as_uint(f);
  unsigned r = x + 0x7fffu + ((x >> 16) & 1u);   // RTNE
  return (unsigned short)(r >> 16);
}
// single-instruction packed f32->bf16 (RTNE), lo = a, hi = b  [T12 recipe]
__device__ __forceinline__ unsigned pk2(float a, float b) {
  unsigned r;
  asm("v_cvt_pk_bf16_f32 %0, %1, %2" : "=v"(r) : "v"(a), "v"(b));
  return r;
}
// 2^x in one v_exp_f32 (softmax runs in log2 domain)
__device__ __forceinline__ float ex2(float x) {
#if __has_builtin(__builtin_amdgcn_exp2f)
  return __builtin_amdgcn_exp2f(x);
#else
  float r; asm("v_exp_f32 %0, %1" : "=v"(r) : "v"(x)); return r;
#endif
}
__device__ __forceinline__ float ldsc(const void* __restrict__ p, int idx, int isf32) {
  return isf32 ? ((const float*)p)[idx] : b2f(((const unsigned short*)p)[idx]);
}

// 16-byte global -> LDS DMA. lds base wave-uniform; HW writes lane i at base+16i.
__device__ __forceinline__ void async_cp16(const unsigned short* g, unsigned short* l) {
  __builtin_amdgcn_global_load_lds(
      (const __attribute__((address_space(1))) unsigned int*)g,
      (__attribute__((address_space(3))) unsigned int*)l, 16, 0, 0);
}

// ---------------------------------------------------------------------------
__global__ void detect_dtype(const unsigned short* __restrict__ cosp, int* __restrict__ flag) {
  const int i = threadIdx.x;   // 64 threads
  const unsigned long long m = __ballot(cosp[i] >= 0x4000u);
  if (i == 0) *flag = (m != 0ull) ? 1 : 0;
}

// ---------------------------------------------------------------------------
// One-shot fp32 -> bf16 conversion of x, w_qkv, w_out (only when inputs fp32).
// ---------------------------------------------------------------------------
__global__ __launch_bounds__(256)
void cvt_all(const float* __restrict__ x, const float* __restrict__ wq,
             const float* __restrict__ wo,
             unsigned short* __restrict__ xb, unsigned short* __restrict__ wqb,
             unsigned short* __restrict__ wob, const int* __restrict__ flag) {
  if (*flag == 0) return;
  const unsigned id = blockIdx.x * 256 + threadIdx.x;  // 0..1048575
  const float* src; unsigned short* dst; unsigned off;
  if (id < 524288u) { src = x; dst = xb; off = id; }
  else if (id < 917504u) { src = wq; dst = wqb; off = id - 524288u; }
  else { src = wo; dst = wob; off = id - 917504u; }
  const float4 a = ((const float4*)src)[off * 2];
  const float4 b = ((const float4*)src)[off * 2 + 1];
  uint4 u;
  u.x = pk2(a.x, a.y); u.y = pk2(a.z, a.w);
  u.z = pk2(b.x, b.y); u.w = pk2(b.z, b.w);
  ((uint4*)dst)[off] = u;
}

// ---------------------------------------------------------------------------
// QKV projection GEMM, 128x128 tile, 512 threads / 8 waves, BK=64, K=1024.
// 2-phase pipeline (issue-early / wait-late). Epilogue: RoPE (q pre-scaled
// by 0.125*log2e), per-wave 32x64 LDS transpose tile, coalesced uint4
// scatter into q/k/v [B,H,T,64] bf16.
// ---------------------------------------------------------------------------
__global__ __launch_bounds__(512, 4)
void gemm_qkv128(const void* __restrict__ Aorig, const unsigned short* __restrict__ Aconv,
                 const void* __restrict__ Worig, const unsigned short* __restrict__ Wconv,
                 const void* __restrict__ cosp, const void* __restrict__ sinp,
                 unsigned short* __restrict__ qout,
                 unsigned short* __restrict__ kout,
                 unsigned short* __restrict__ vout,
                 const int* __restrict__ dflag) {
  const int f32flag = *dflag;
  const unsigned short* A = f32flag ? Aconv : (const unsigned short*)Aorig;
  const unsigned short* W = f32flag ? Wconv : (const unsigned short*)Worig;

  const int tid = threadIdx.x;
  const int m0 = blockIdx.y * 128;
  const int n0 = blockIdx.x * 128;

  __shared__ __align__(16) unsigned short s_ab[2 * 16384];

  const int lane = tid & 63;
  const int wave = tid >> 6;               // 0..7
  const int wm = (wave & 3) * 32;
  const int wn = (wave >> 2) * 64;
  const int m16 = lane & 15;
  const int quad = lane >> 4;

  const int srow = lane >> 3;
  const int schunk = (lane & 7) ^ srow;

  const unsigned short* ga = A + (size_t)(m0 + wave * 8 + srow) * DIMC + schunk * 8;
  const unsigned short* gb = W + (size_t)(n0 + wave * 8 + srow) * DIMC + schunk * 8;

  f32x4 acc[2][4];
#pragma unroll
  for (int i = 0; i < 2; ++i)
#pragma unroll
    for (int j = 0; j < 4; ++j) acc[i][j] = (f32x4){0.f, 0.f, 0.f, 0.f};

  auto stage = [&](int b, int kt) {
    unsigned short* sa = s_ab + b * 16384;
#pragma unroll
    for (int u = 0; u < 2; ++u) {
      async_cp16(ga + (size_t)(u * 64) * DIMC + kt, &sa[(u * 64 + wave * 8) * 64]);
      async_cp16(gb + (size_t)(u * 64) * DIMC + kt, &sa[8192 + (u * 64 + wave * 8) * 64]);
    }
  };

  stage(0, 0);
  __syncthreads();

  for (int t = 0; t < 16; ++t) {
    const int cur = t & 1;
    if (t < 15) stage(cur ^ 1, (t + 1) * 64);
    const unsigned short* sa = s_ab + cur * 16384;
    const unsigned short* sb = sa + 8192;
    __builtin_amdgcn_s_setprio(1);
#pragma unroll
    for (int kk = 0; kk < 64; kk += 32) {
      const int cx = ((kk >> 3) + quad) ^ (m16 & 7);
      s16x8 af[2], bf[4];
#pragma unroll
      for (int i = 0; i < 2; ++i)
        af[i] = *(const s16x8*)&sa[(wm + i * 16 + m16) * 64 + cx * 8];
#pragma unroll
      for (int j = 0; j < 4; ++j)
        bf[j] = *(const s16x8*)&sb[(wn + j * 16 + m16) * 64 + cx * 8];
#pragma unroll
      for (int i = 0; i < 2; ++i)
#pragma unroll
        for (int j = 0; j < 4; ++j)
          acc[i][j] = __builtin_amdgcn_mfma_f32_16x16x32_bf16(af[i], bf[j], acc[i][j], 0, 0, 0);
    }
    __builtin_amdgcn_s_setprio(0);
    __syncthreads();
  }

  const int sel = n0 >> 10;
  const int h = ((n0 & 1023) >> 6) + (wave >> 2);
  unsigned short* dst = (sel == 0) ? qout : ((sel == 1) ? kout : vout);
  const float qsc = (sel == 0) ? 0.18033688f : 1.0f;
  unsigned short* tile = s_ab + wave * 2048;
  if (sel < 2) {
#pragma unroll
    for (int i = 0; i < 2; ++i)
#pragma unroll
      for (int r = 0; r < 4; ++r) {
        const int row_l = i * 16 + quad * 4 + r;
        const int t = (m0 + wm + row_l) & 2047;
#pragma unroll
        for (int jg = 0; jg < 2; ++jg) {
          const int d = jg * 16 + m16;
          const float c = ldsc(cosp, t * 32 + d, f32flag);
          const float sn = ldsc(sinp, t * 32 + d, f32flag);
          const float v1 = acc[i][jg][r];
          const float v2 = acc[i][jg + 2][r];
          tile[row_l * 64 + d]      = f2b((v1 * c - v2 * sn) * qsc);
          tile[row_l * 64 + d + 32] = f2b((v1 * sn + v2 * c) * qsc);
        }
      }
  } else {
#pragma unroll
    for (int i = 0; i < 2; ++i)
#pragma unroll
      for (int r = 0; r < 4; ++r) {
        const int row_l = i * 16 + quad * 4 + r;
#pragma unroll
        for (int j = 0; j < 4; ++j)
          tile[row_l * 64 + j * 16 + m16] = f2b(acc[i][j][r]);
      }
  }
#pragma unroll
  for (int s = 0; s < 4; ++s) {
    const int row_l = s * 8 + (lane >> 3);
    const int seg = lane & 7;
    const int mrow_ = m0 + wm + row_l;
    const int bb = mrow_ >> 11;
    const int t = mrow_ & 2047;
    unsigned short* drow = dst + (((size_t)(bb * NH + h)) * TSZ + t) * HD;
    *(uint4*)(drow + seg * 8) = *(const uint4*)&tile[row_l * 64 + seg * 8];
  }
}

// ---------------------------------------------------------------------------
// Out-projection GEMM: 128x64 tile, 256 threads / 4 waves, 2-phase
// issue-early/wait-late pipeline (LDS 2 x 24 KB). fp32 epilogue: per-wave
// 32x68-stride LDS transpose then coalesced float4 stores.
// ---------------------------------------------------------------------------
__global__ __launch_bounds__(256)
void gemm_out(const void* __restrict__ Aorig, const unsigned short* __restrict__ Aconv,
              const void* __restrict__ Worig, const unsigned short* __restrict__ Wconv,
              void* __restrict__ C, const int* __restrict__ dflag, int Nsz) {
  const int f32flag = *dflag;
  const unsigned short* A = f32flag ? Aconv : (const unsigned short*)Aorig;
  const unsigned short* W = f32flag ? Wconv : (const unsigned short*)Worig;

  const int tid = threadIdx.x;
  const int m0 = blockIdx.y * 128;
  const int n0 = blockIdx.x * 64;

  __shared__ __align__(16) unsigned short s_ab[2 * 12288];

  const int lane = tid & 63;
  const int wave = tid >> 6;               // 0..3
  const int wm = wave * 32;
  const int m16 = lane & 15;
  const int quad = lane >> 4;

  const int srow = lane >> 3;
  const int schunk = (lane & 7) ^ srow;

  const unsigned short* ga = A + (size_t)(m0 + wave * 8 + srow) * DIMC + schunk * 8;
  const unsigned short* gb = W + (size_t)(n0 + wave * 8 + srow) * DIMC + schunk * 8;

  f32x4 acc[2][4];
#pragma unroll
  for (int i = 0; i < 2; ++i)
#pragma unroll
    for (int j = 0; j < 4; ++j) acc[i][j] = (f32x4){0.f, 0.f, 0.f, 0.f};

  auto stage = [&](int b, int kt) {
    unsigned short* sa = s_ab + b * 12288;
#pragma unroll
    for (int u = 0; u < 4; ++u)
      async_cp16(ga + (size_t)(u * 32) * DIMC + kt, &sa[(u * 32 + wave * 8) * 64]);
#pragma unroll
    for (int u = 0; u < 2; ++u)
      async_cp16(gb + (size_t)(u * 32) * DIMC + kt, &sa[8192 + (u * 32 + wave * 8) * 64]);
  };

  stage(0, 0);
  __syncthreads();

  for (int t = 0; t < 16; ++t) {
    const int cur = t & 1;
    if (t < 15) stage(cur ^ 1, (t + 1) * 64);
    const unsigned short* sa = s_ab + cur * 12288;
    const unsigned short* sb = sa + 8192;
    __builtin_amdgcn_s_setprio(1);
#pragma unroll
    for (int kk = 0; kk < 64; kk += 32) {
      const int cx = ((kk >> 3) + quad) ^ (m16 & 7);
      s16x8 af[2], bf[4];
#pragma unroll
      for (int i = 0; i < 2; ++i)
        af[i] = *(const s16x8*)&sa[(wm + i * 16 + m16) * 64 + cx * 8];
#pragma unroll
      for (int j = 0; j < 4; ++j)
        bf[j] = *(const s16x8*)&sb[(j * 16 + m16) * 64 + cx * 8];
#pragma unroll
      for (int i = 0; i < 2; ++i)
#pragma unroll
        for (int j = 0; j < 4; ++j)
          acc[i][j] = __builtin_amdgcn_mfma_f32_16x16x32_bf16(af[i], bf[j], acc[i][j], 0, 0, 0);
    }
    __builtin_amdgcn_s_setprio(0);
    __syncthreads();
  }

  if (f32flag) {
    float* ftile = (float*)s_ab + wave * (32 * 68);
#pragma unroll
    for (int i = 0; i < 2; ++i)
#pragma unroll
      for (int j = 0; j < 4; ++j)
#pragma unroll
        for (int r = 0; r < 4; ++r)
          ftile[(i * 16 + quad * 4 + r) * 68 + j * 16 + m16] = acc[i][j][r];
    float* Cf = (float*)C;
#pragma unroll
    for (int i = 0; i < 2; ++i)
#pragma unroll
      for (int s = 0; s < 4; ++s) {
        const int row_l = i * 16 + s * 4 + (lane >> 4);
        const float4 vv = *(const float4*)&ftile[row_l * 68 + (lane & 15) * 4];
        *(float4*)&Cf[(size_t)(m0 + wm + row_l) * Nsz + n0 + (lane & 15) * 4] = vv;
      }
  } else {
    unsigned short* Ch = (unsigned short*)C;
#pragma unroll
    for (int i = 0; i < 2; ++i)
#pragma unroll
      for (int j = 0; j < 4; ++j)
#pragma unroll
        for (int r = 0; r < 4; ++r) {
          const int mrow_ = m0 + wm + i * 16 + quad * 4 + r;
          const int col = n0 + j * 16 + m16;
          Ch[(size_t)mrow_ * Nsz + col] = f2b(acc[i][j][r]);
        }
  }
}

// ---------------------------------------------------------------------------
// MFMA flash attention — champion configuration (44.2-44.6 us across four
// independent runs). S^T form, 512 threads (8 waves), KVBLK=128,
// XOR-swizzled K/V^T/P LDS (64 KB, 2 blocks/CU = 16 waves/CU, grid-capped).
// Falsified alternatives (rounds 9-14): 32q/wave wave-widening (-2x:
// needs >=16 waves/CU), K-direct-from-global (-2.2x: vmem latency enters
// MFMA dep chain), tree-reduce (neutral), speculative defer-max (-3%).
// The kernel is dependency-latency-bound; further gains need the full
// co-designed pipeline combo (T16), not single levers. Front/back mirror
// subtile fusion, log2-domain softmax, defer-max THR=8, cvt_pk packing,
// setprio around MFMA clusters.
// ---------------------------------------------------------------------------
__global__ __launch_bounds__(512, 4)
void attn_fwd_mfma(const unsigned short* __restrict__ qg,
                   const unsigned short* __restrict__ kg,
                   const unsigned short* __restrict__ vg,
                   unsigned short* __restrict__ outg) {
  const int tid = threadIdx.x;
  const int lane = tid & 63;
  const int w = tid >> 6;                // wave 0..7
  const int m16 = lane & 15;
  const int quad = lane >> 4;
  const int sw = m16 & 7;                // row-XOR swizzle key for this lane
  const int l = (int)blockIdx.x;         // 0..511
  const int g = (l & 255) >> 5;          // 0..7
  const int p = (l < 256) ? g : (15 - g);
  const int nc = (33 - p) >> 1;          // 128-key chunks for back subtile 31-p
  const int bh = l & 31;
  const int b = bh >> 4, h = bh & 15;
  const size_t base = (size_t)bh * TSZ * HD;
  const int sub = (w < 4) ? p : (31 - p);
  const int qs = sub * 64 + (w & 3) * 16;   // wave's first query row

  __shared__ __align__(16) unsigned short s_k[128 * 64];   // K rows (16 KB)
  __shared__ __align__(16) unsigned short s_v[64 * 128];   // V^T (16 KB)
  __shared__ __align__(16) unsigned short s_p[128 * 128];  // P + epilogue (32 KB)

  const unsigned short* qgh = qg + base;
  const unsigned short* kgh = kg + base;
  const unsigned short* vgh = vg + base;

  const unsigned short* qrow = qgh + (size_t)(qs + m16) * HD;
  const s16x8 bq0 = *(const s16x8*)(qrow + quad * 8);
  const s16x8 bq1 = *(const s16x8*)(qrow + 32 + quad * 8);

  f32x4 oacc[4];
#pragma unroll
  for (int dt = 0; dt < 4; ++dt) oacc[dt] = (f32x4){0.f, 0.f, 0.f, 0.f};
  float m_ = -1e30f, l_ = 0.f;

  const int krow = tid >> 3, kseg = tid & 7;   // K: 2 rows/thread (r, r+64)
  const int vkey = tid & 63, vseg = tid >> 6;  // V: keys (vkey, vkey+64), 8 d
  const int kcol = (kseg ^ (krow & 7)) * 8;    // swizzled K LDS column
  const int vc0 = vkey >> 3, vo0 = vkey & 7;   // V key chunk / within-chunk

  {  // prologue: chunk 0 into LDS (swizzled)
    const uint4 a0 = *(const uint4*)(kgh + (size_t)krow * HD + kseg * 8);
    const uint4 a1 = *(const uint4*)(kgh + (size_t)(64 + krow) * HD + kseg * 8);
    const uint4 b0 = *(const uint4*)(vgh + (size_t)vkey * HD + vseg * 8);
    const uint4 b1 = *(const uint4*)(vgh + (size_t)(64 + vkey) * HD + vseg * 8);
    *(uint4*)&s_k[krow * 64 + kcol] = a0;
    *(uint4*)&s_k[(64 + krow) * 64 + kcol] = a1;
    const unsigned short* v0 = (const unsigned short*)&b0;
    const unsigned short* v1 = (const unsigned short*)&b1;
#pragma unroll
    for (int jj = 0; jj < 8; ++jj) {
      const int dr = (vseg * 8 + jj) * 128;
      s_v[dr + (vc0 ^ jj) * 8 + vo0] = v0[jj];
      s_v[dr + ((8 + vc0) ^ jj) * 8 + vo0] = v1[jj];
    }
  }

  for (int kc = 0; kc < nc; ++kc) {
    __syncthreads();                     // chunk kc staged & visible
    uint4 a0, a1, b0, b1;
    const int pf = (kc + 1 < nc);
    if (pf) {                            // prefetch next chunk (flies in regs)
      const size_t ko = (size_t)(kc + 1) * 128;
      a0 = *(const uint4*)(kgh + (ko + krow) * HD + kseg * 8);
      a1 = *(const uint4*)(kgh + (ko + 64 + krow) * HD + kseg * 8);
      b0 = *(const uint4*)(vgh + (ko + vkey) * HD + vseg * 8);
      b1 = *(const uint4*)(vgh + (ko + 64 + vkey) * HD + vseg * 8);
    }

    if (kc * 128 <= qs + 15) {           // not fully masked for this wave
      f32x4 sacc[8];
#pragma unroll
      for (int jt = 0; jt < 8; ++jt) sacc[jt] = (f32x4){0.f, 0.f, 0.f, 0.f};
      __builtin_amdgcn_s_setprio(1);
#pragma unroll
      for (int jt = 0; jt < 8; ++jt) {
        const int krb = (jt * 16 + m16) * 64;
        const s16x8 ak0 = *(const s16x8*)&s_k[krb + (quad ^ sw) * 8];
        sacc[jt] = __builtin_amdgcn_mfma_f32_16x16x32_bf16(ak0, bq0, sacc[jt], 0, 0, 0);
        const s16x8 ak1 = *(const s16x8*)&s_k[krb + ((4 + quad) ^ sw) * 8];
        sacc[jt] = __builtin_amdgcn_mfma_f32_16x16x32_bf16(ak1, bq1, sacc[jt], 0, 0, 0);
      }
      __builtin_amdgcn_s_setprio(0);

      if (kc * 128 + 127 > qs) {         // diagonal region: element mask
#pragma unroll
        for (int jt = 0; jt < 8; ++jt)
#pragma unroll
          for (int r = 0; r < 4; ++r)
            if (kc * 128 + jt * 16 + quad * 4 + r > qs + m16) sacc[jt][r] = -1e30f;
      }

      float mx = sacc[0][0];
#pragma unroll
      for (int jt = 0; jt < 8; ++jt)
#pragma unroll
        for (int r = 0; r < 4; ++r) mx = fmaxf(mx, sacc[jt][r]);
      mx = fmaxf(mx, __shfl_xor(mx, 16, 64));
      mx = fmaxf(mx, __shfl_xor(mx, 32, 64));
      if (!__all(mx <= m_ + 8.0f)) {     // defer-max
        const float mn = fmaxf(m_, mx);
        const float alpha = ex2(m_ - mn);
        m_ = mn;
        l_ *= alpha;
#pragma unroll
        for (int dt = 0; dt < 4; ++dt)
#pragma unroll
          for (int r = 0; r < 4; ++r) oacc[dt][r] *= alpha;
      }
      float rs = 0.f;
#pragma unroll
      for (int jt = 0; jt < 8; ++jt)
#pragma unroll
        for (int r = 0; r < 4; ++r) {
          const float pv_ = ex2(sacc[jt][r] - m_);
          sacc[jt][r] = pv_;
          rs += pv_;
        }
      rs += __shfl_xor(rs, 16, 64);
      rs += __shfl_xor(rs, 32, 64);
      l_ += rs;

      const int prb = (w * 16 + m16) * 128;
#pragma unroll
      for (int jt = 0; jt < 8; ++jt) {
        uint2 pw;
        pw.x = pk2(sacc[jt][0], sacc[jt][1]);
        pw.y = pk2(sacc[jt][2], sacc[jt][3]);
        *(uint2*)&s_p[prb + ((jt * 2 + (quad >> 1)) ^ sw) * 8 + (quad & 1) * 4] = pw;
      }

      __builtin_amdgcn_s_setprio(1);
#pragma unroll
      for (int kk = 0; kk < 128; kk += 32) {
        const int cx = (((kk >> 3) + quad) ^ sw) * 8;
        const s16x8 bp = *(const s16x8*)&s_p[prb + cx];
#pragma unroll
        for (int dt = 0; dt < 4; ++dt) {
          const s16x8 av = *(const s16x8*)&s_v[(dt * 16 + m16) * 128 + cx];
          oacc[dt] = __builtin_amdgcn_mfma_f32_16x16x32_bf16(av, bp, oacc[dt], 0, 0, 0);
        }
      }
      __builtin_amdgcn_s_setprio(0);
    }

    __syncthreads();                     // all reads of chunk kc done
    if (pf) {                            // single-buffer write of chunk kc+1
      *(uint4*)&s_k[krow * 64 + kcol] = a0;
      *(uint4*)&s_k[(64 + krow) * 64 + kcol] = a1;
      const unsigned short* v0 = (const unsigned short*)&b0;
      const unsigned short* v1 = (const unsigned short*)&b1;
#pragma unroll
      for (int jj = 0; jj < 8; ++jj) {
        const int dr = (vseg * 8 + jj) * 128;
        s_v[dr + (vc0 ^ jj) * 8 + vo0] = v0[jj];
        s_v[dr + ((8 + vc0) ^ jj) * 8 + vo0] = v1[jj];
      }
    }
  }

  // epilogue: normalize, transpose via wave-private s_p rows, coalesced store
  const float linv = 1.0f / l_;
  {
    const int prb = (w * 16 + m16) * 128;
#pragma unroll
    for (int dt = 0; dt < 4; ++dt) {
      uint2 ow;
      ow.x = pk2(oacc[dt][0] * linv, oacc[dt][1] * linv);
      ow.y = pk2(oacc[dt][2] * linv, oacc[dt][3] * linv);
      *(uint2*)&s_p[prb + ((dt * 2 + (quad >> 1)) ^ sw) * 8 + (quad & 1) * 4] = ow;
    }
  }
  {
    const int qq = lane >> 2, dseg = lane & 3;   // wave-private rows: no barrier
    const int swq = qq & 7;
    const int qrb = (w * 16 + qq) * 128;
    const uint4 o0 = *(const uint4*)&s_p[qrb + ((dseg * 2) ^ swq) * 8];
    const uint4 o1 = *(const uint4*)&s_p[qrb + ((dseg * 2 + 1) ^ swq) * 8];
    unsigned short* orow =
        outg + ((size_t)b * TSZ + qs + qq) * DIMC + h * 64 + dseg * 16;
    *(uint4*)orow = o0;
    *(uint4*)(orow + 8) = o1;
  }
}

// ---------------------------------------------------------------------------
extern "C" void kernel_launch(void* const* d_in, const int* in_sizes, int n_in,
                              void* d_out, int out_size, void* d_ws, size_t ws_size,
                              hipStream_t stream) {
  (void)in_sizes; (void)n_in; (void)out_size; (void)ws_size;
  const void* x    = d_in[0];
  const void* cosp = d_in[1];
  const void* sinp = d_in[2];
  const void* wqkv = d_in[3];
  const void* wout = d_in[4];

  int* dflag = (int*)d_ws;
  const size_t per = (size_t)BSZ * NH * TSZ * HD;       // 4,194,304 elems
  unsigned short* q = (unsigned short*)((char*)d_ws + 256);
  unsigned short* k = q + per;
  unsigned short* v = k + per;
  unsigned short* attnb = v + per;                      // [B,T,DIM] bf16
  unsigned short* xb   = attnb + (size_t)MROWS * DIMC;  // bf16 copies (fp32 case)
  unsigned short* wqb  = xb + (size_t)MROWS * DIMC;
  unsigned short* wob  = wqb + (size_t)3 * DIMC * DIMC;

  detect_dtype<<<1, 64, 0, stream>>>((const unsigned short*)cosp, dflag);
  cvt_all<<<dim3(4096), dim3(256), 0, stream>>>(
      (const float*)x, (const float*)wqkv, (const float*)wout, xb, wqb, wob, dflag);
  // QKV projection: 128x128 tiles, 512 threads, 2-phase pipeline
  gemm_qkv128<<<dim3(3 * DIMC / 128, MROWS / 128), dim3(512), 0, stream>>>(
      x, xb, wqkv, wqb, cosp, sinp, q, k, v, dflag);
  // causal flash attention: champion (512 blocks x 8 waves, KVBLK=128, swizzled)
  attn_fwd_mfma<<<dim3(512), dim3(512), 0, stream>>>(q, k, v, attnb);
  // out-projection: 128x64 tiles, 256 threads, 2-phase pipeline
  gemm_out<<<dim3(DIMC / 64, MROWS / 128), dim3(256), 0, stream>>>(
      attnb, attnb, wout, wob, d_out, dflag, DIMC);
}